// Round 3
// baseline (146.459 us; speedup 1.0000x reference)
//
#include <hip/hip_runtime.h>
#include <math.h>

#define NN 65536
#define MM 16384
#define EE 524288
#define CF 64
#define HD 128
#define OD 256
#define GPB 4   // 64-edge groups per block

typedef __bf16 bf16x8 __attribute__((ext_vector_type(8)));
typedef __bf16 bf16x4 __attribute__((ext_vector_type(4)));
typedef float f32x4 __attribute__((ext_vector_type(4)));

// order-isomorphic float->uint encoding so segment-max can use atomicMax(uint)
__device__ __forceinline__ unsigned enc_f(float f) {
    unsigned u = __float_as_uint(f);
    return (u & 0x80000000u) ? ~u : (u | 0x80000000u);
}
__device__ __forceinline__ float dec_f(unsigned e) {
    unsigned u = (e & 0x80000000u) ? (e ^ 0x80000000u) : ~e;
    return __uint_as_float(u);
}
#define ENC_NEG_INF 0x007FFFFFu  // enc(-inf)

// DPP shuffles within 16-lane rows (VALU pipe, no LDS traffic).
// row_shr:N = 0x110|N : lane i <- lane i-N (shfl_up). row_shl:1 = 0x101 (shfl_down 1).
template <int N>
__device__ __forceinline__ int shup_i(int v) {
    return __builtin_amdgcn_update_dpp(v, v, 0x110 | N, 0xF, 0xF, false);
}
template <int N>
__device__ __forceinline__ float shup_f(float v) {
    return __builtin_bit_cast(float, shup_i<N>(__builtin_bit_cast(int, v)));
}
__device__ __forceinline__ int shdn1_i(int v) {
    return __builtin_amdgcn_update_dpp(v, v, 0x101, 0xF, 0xF, false);
}

template <int OFF>
__device__ __forceinline__ void segstep(int r, int ln, float (&v)[8]) {
    int rn = shup_i<OFF>(r);
    bool ok = (ln >= OFF) && (rn == r);
    #pragma unroll
    for (int i = 0; i < 8; ++i) {
        float vn = shup_f<OFF>(v[i]);
        if (ok) v[i] = fmaxf(v[i], vn);
    }
}

__global__ void k_init(unsigned* __restrict__ agg) {
    int i = blockIdx.x * 256 + threadIdx.x;
    if (i < MM * HD) agg[i] = ENC_NEG_INF;
}

__global__ void k_prep(const float* __restrict__ pos, const int* __restrict__ batch,
                       const int* __restrict__ idx, float* __restrict__ out) {
    int m = blockIdx.x * 256 + threadIdx.x;
    if (m >= MM) return;
    int s = idx[m];
    out[MM * OD + m * 3 + 0] = pos[s * 3 + 0];
    out[MM * OD + m * 3 + 1] = pos[s * 3 + 1];
    out[MM * OD + m * 3 + 2] = pos[s * 3 + 2];
    out[MM * OD + MM * 3 + m] = (float)batch[s];
}

// MFMA edge kernel, swapped operands: D[n][e] = sum_k W[k][n] * ein[e][k].
// LDS rows are 128 bf16 = 16 chunks of 16B; chunk index is XOR-swizzled with (e&7).
__launch_bounds__(256, 3)
__global__ void k_edge(const float* __restrict__ x, const float* __restrict__ pos,
                       const int* __restrict__ idx, const int* __restrict__ row,
                       const int* __restrict__ col,
                       const float* __restrict__ lw1, const float* __restrict__ lb1,
                       const float* __restrict__ lw2, const float* __restrict__ lb2,
                       unsigned* __restrict__ agg) {
    __shared__ __align__(16) __bf16 ein[64][HD];
    __shared__ __align__(16) __bf16 hbuf[64][HD];
    __shared__ int srow[64];
    const int t = threadIdx.x;
    const int lane = t & 63;
    const int wv = t >> 6;          // wave id: owns n in [wv*32, wv*32+32)
    const int q = lane >> 4;
    const int ln = lane & 15;
    const int lsw = ln & 7;         // e&7 for e = et*16+ln

    // ---- weight fragments as MFMA *A* operand: row(=n) = ln, k = q*8+j ----
    bf16x8 w1f[2][4], w2f[2][4];
    float b1v[2][4], b2v[2][4];
    #pragma unroll
    for (int mt = 0; mt < 2; ++mt) {
        const int n = wv * 32 + mt * 16 + ln;
        #pragma unroll
        for (int rr = 0; rr < 4; ++rr) {
            b1v[mt][rr] = lb1[wv * 32 + mt * 16 + q * 4 + rr];
            b2v[mt][rr] = lb2[wv * 32 + mt * 16 + q * 4 + rr];
        }
        #pragma unroll
        for (int kk = 0; kk < 4; ++kk) {
            #pragma unroll
            for (int j = 0; j < 8; ++j) {
                const int k = kk * 32 + q * 8 + j;
                w1f[mt][kk][j] = (__bf16)((k < 127) ? lw1[k * HD + n] : 0.0f);
                w2f[mt][kk][j] = (__bf16)lw2[k * HD + n];
            }
        }
    }

    for (int g = 0; g < GPB; ++g) {
        const int e0 = (blockIdx.x * GPB + g) * 64;
        if (g) __syncthreads();  // protect ein/srow until all waves finish group g-1

        // ---- stage x[col] -> ein[:,0:64] (4 threads/edge, two swizzled b128 stores) ----
        {
            const int e = t >> 2, part = t & 3;
            const int c = col[e0 + e];
            const float4* xr = (const float4*)(x + (size_t)c * CF);
            const int esw = e & 7;
            #pragma unroll
            for (int s = 0; s < 2; ++s) {
                float4 va = xr[part * 4 + s * 2 + 0];
                float4 vb = xr[part * 4 + s * 2 + 1];
                bf16x8 pk;
                pk[0] = (__bf16)va.x; pk[1] = (__bf16)va.y; pk[2] = (__bf16)va.z; pk[3] = (__bf16)va.w;
                pk[4] = (__bf16)vb.x; pk[5] = (__bf16)vb.y; pk[6] = (__bf16)vb.z; pk[7] = (__bf16)vb.w;
                *(bf16x8*)&ein[e][((part * 2 + s) ^ esw) * 8] = pk;
            }
        }
        // ---- positional encoding, 192 threads: (e, d) = (t&63, t>>6) ----
        if (t < 192) {
            const int e = t & 63, d = t >> 6;
            const int r = row[e0 + e];
            const int c = col[e0 + e];
            const int s = idx[r];
            const int esw = e & 7;
            if (d == 0) {
                srow[e] = r;
                ein[e][(15 ^ esw) * 8 + 7] = (__bf16)0.0f;  // K pad, col 127
            }
            float pd = pos[c * 3 + d] - pos[s * 3 + d];
            { const int j = 64 + d; ein[e][((j >> 3) ^ esw) * 8 + (j & 7)] = (__bf16)pd; }
            float f = pd * 3.14159265358979323846f;
            float sv, cv;
            sincosf(f, &sv, &cv);
            #pragma unroll
            for (int l = 0; l < 10; ++l) {
                int j = 67 + d * 20 + l * 2;
                ein[e][((j >> 3) ^ esw) * 8 + (j & 7)] = (__bf16)sv;
                ++j;
                ein[e][((j >> 3) ^ esw) * 8 + (j & 7)] = (__bf16)cv;
                const float s2 = 2.0f * sv * cv;          // sin(2t) = 2 s c
                const float c2 = 1.0f - 2.0f * sv * sv;   // cos(2t) = 1 - 2 s^2
                sv = s2; cv = c2;
            }
        }
        __syncthreads();

        f32x4 acc[2][4];

        // ---- GEMM1: D[n][e], n-tiles mt(2), e-tiles et(4), K=128 ----
        #pragma unroll
        for (int mt = 0; mt < 2; ++mt)
            #pragma unroll
            for (int et = 0; et < 4; ++et)
                acc[mt][et] = (f32x4){b1v[mt][0], b1v[mt][1], b1v[mt][2], b1v[mt][3]};
        #pragma unroll
        for (int et = 0; et < 4; ++et) {
            const int e = et * 16 + ln;
            #pragma unroll
            for (int kk = 0; kk < 4; ++kk) {
                bf16x8 a = *(const bf16x8*)&ein[e][((kk * 4 + q) ^ lsw) * 8];
                acc[0][et] = __builtin_amdgcn_mfma_f32_16x16x32_bf16(w1f[0][kk], a, acc[0][et], 0, 0, 0);
                acc[1][et] = __builtin_amdgcn_mfma_f32_16x16x32_bf16(w1f[1][kk], a, acc[1][et], 0, 0, 0);
            }
        }
        // relu + pack 4 consecutive n per lane -> b64 swizzled store
        #pragma unroll
        for (int et = 0; et < 4; ++et) {
            const int e = et * 16 + ln;
            #pragma unroll
            for (int mt = 0; mt < 2; ++mt) {
                bf16x4 hv;
                hv[0] = (__bf16)fmaxf(acc[mt][et][0], 0.0f);
                hv[1] = (__bf16)fmaxf(acc[mt][et][1], 0.0f);
                hv[2] = (__bf16)fmaxf(acc[mt][et][2], 0.0f);
                hv[3] = (__bf16)fmaxf(acc[mt][et][3], 0.0f);
                const int chunk = wv * 4 + mt * 2 + (q >> 1);
                *(bf16x4*)&hbuf[e][((chunk ^ lsw) * 8) + (q & 1) * 4] = hv;
            }
        }
        __syncthreads();

        // ---- GEMM2: ef[n][e] from hbuf ----
        #pragma unroll
        for (int mt = 0; mt < 2; ++mt)
            #pragma unroll
            for (int et = 0; et < 4; ++et)
                acc[mt][et] = (f32x4){b2v[mt][0], b2v[mt][1], b2v[mt][2], b2v[mt][3]};
        #pragma unroll
        for (int et = 0; et < 4; ++et) {
            const int e = et * 16 + ln;
            #pragma unroll
            for (int kk = 0; kk < 4; ++kk) {
                bf16x8 a = *(const bf16x8*)&hbuf[e][((kk * 4 + q) ^ lsw) * 8];
                acc[0][et] = __builtin_amdgcn_mfma_f32_16x16x32_bf16(w2f[0][kk], a, acc[0][et], 0, 0, 0);
                acc[1][et] = __builtin_amdgcn_mfma_f32_16x16x32_bf16(w2f[1][kk], a, acc[1][et], 0, 0, 0);
            }
        }

        // ---- in-register segment max over the 16 edge-lanes, then leader atomics ----
        #pragma unroll
        for (int et = 0; et < 4; ++et) {
            const int e = et * 16 + ln;
            int r = srow[e];
            float v[8];
            #pragma unroll
            for (int i = 0; i < 4; ++i) { v[i] = acc[0][et][i]; v[4 + i] = acc[1][et][i]; }
            segstep<1>(r, ln, v);
            segstep<2>(r, ln, v);
            segstep<4>(r, ln, v);
            segstep<8>(r, ln, v);
            const int rnext = shdn1_i(r);
            const bool leader = (ln == 15) || (rnext != r);
            if (leader) {
                #pragma unroll
                for (int mt = 0; mt < 2; ++mt)
                    #pragma unroll
                    for (int rr = 0; rr < 4; ++rr)
                        atomicMax(&agg[(size_t)r * HD + wv * 32 + mt * 16 + q * 4 + rr],
                                  enc_f(v[mt * 4 + rr]));
            }
        }
    }
}

// out = decode(agg) @ gw + gb, empty rows -> 0
__launch_bounds__(256, 4)
__global__ void k_out(const unsigned* __restrict__ agg, const float* __restrict__ gw,
                      const float* __restrict__ gb, float* __restrict__ out) {
    __shared__ float a[32][HD];
    const int t = threadIdx.x;
    const int m0 = blockIdx.x * 32;
    for (int i = t; i < 32 * HD; i += 256) {
        unsigned e = agg[(size_t)m0 * HD + i];
        a[i >> 7][i & 127] = (e == ENC_NEG_INF) ? 0.0f : dec_f(e);
    }
    __syncthreads();
    const int j4 = (t & 63) * 4;
    const int rbase = (t >> 6) * 8;
    float acc[8][4];
    const float4 bias = *(const float4*)&gb[j4];
    #pragma unroll
    for (int r = 0; r < 8; ++r) { acc[r][0] = bias.x; acc[r][1] = bias.y; acc[r][2] = bias.z; acc[r][3] = bias.w; }
    for (int k = 0; k < 128; k += 4) {
        float4 w0 = *(const float4*)&gw[(k + 0) * OD + j4];
        float4 w1 = *(const float4*)&gw[(k + 1) * OD + j4];
        float4 w2 = *(const float4*)&gw[(k + 2) * OD + j4];
        float4 w3 = *(const float4*)&gw[(k + 3) * OD + j4];
        #pragma unroll
        for (int r = 0; r < 8; ++r) {
            float4 av = *(const float4*)&a[rbase + r][k];
            acc[r][0] += av.x * w0.x + av.y * w1.x + av.z * w2.x + av.w * w3.x;
            acc[r][1] += av.x * w0.y + av.y * w1.y + av.z * w2.y + av.w * w3.y;
            acc[r][2] += av.x * w0.z + av.y * w1.z + av.z * w2.z + av.w * w3.z;
            acc[r][3] += av.x * w0.w + av.y * w1.w + av.z * w2.w + av.w * w3.w;
        }
    }
    #pragma unroll
    for (int r = 0; r < 8; ++r) {
        float4 v; v.x = acc[r][0]; v.y = acc[r][1]; v.z = acc[r][2]; v.w = acc[r][3];
        *(float4*)&out[(size_t)(m0 + rbase + r) * OD + j4] = v;
    }
}

extern "C" void kernel_launch(void* const* d_in, const int* in_sizes, int n_in,
                              void* d_out, int out_size, void* d_ws, size_t ws_size,
                              hipStream_t stream) {
    const float* x   = (const float*)d_in[0];
    const float* pos = (const float*)d_in[1];
    const int* batch = (const int*)d_in[2];
    const int* idx   = (const int*)d_in[3];
    const int* row   = (const int*)d_in[4];
    const int* col   = (const int*)d_in[5];
    const float* lw1 = (const float*)d_in[6];
    const float* lb1 = (const float*)d_in[7];
    const float* lw2 = (const float*)d_in[8];
    const float* lb2 = (const float*)d_in[9];
    const float* gw  = (const float*)d_in[10];
    const float* gb  = (const float*)d_in[11];
    float* out = (float*)d_out;
    unsigned* agg = (unsigned*)d_ws;  // MM*HD*4 = 8 MB

    hipLaunchKernelGGL(k_init, dim3((MM * HD + 255) / 256), dim3(256), 0, stream, agg);
    hipLaunchKernelGGL(k_prep, dim3((MM + 255) / 256), dim3(256), 0, stream, pos, batch, idx, out);
    hipLaunchKernelGGL(k_edge, dim3(EE / (64 * GPB)), dim3(256), 0, stream,
                       x, pos, idx, row, col, lw1, lb1, lw2, lb2, agg);
    hipLaunchKernelGGL(k_out, dim3(MM / 32), dim3(256), 0, stream, agg, gw, gb, out);
}